// Round 6
// baseline (78.925 us; speedup 1.0000x reference)
//
#include <hip/hip_runtime.h>

// left/right: [B=4, C=32, H=64, W=128] fp32 ; out: [B, 2C=64, D=48, H, W] fp32
#define BB 4
#define CC 32
#define HH 64
#define WW 128
#define DD 48
#define DG 6                  // d-planes per block
#define PLANE (HH * WW)       // 8192 floats = 32 KB
#define RSTRIDE 160           // swizzled LDS row stride

typedef float f32x4 __attribute__((ext_vector_type(4)));

// Grid = 2048 blocks x 512 threads. Block = (half, b, c, dgrp): owns a
// CONTIGUOUS 192 KB output span (6 d-planes of one (b,c2)) and sweeps it
// linearly — same store stream shape as fillBufferAligned (6.9 TB/s here).
//   left blocks : 4 float4/thread held in registers, mask per d, store.
//   right blocks: stage full 32 KB plane in LDS once (swizzled, conflict-free
//                 gather), reuse across 6 d.
// XCD swizzle: bx = ((slot*8 + dgrp)<<3) | xcd with xcd = g&7, slot = g>>3,
// g = half*128 + b*32 + c — all 8 dgrp-blocks of a group land on ONE XCD in
// consecutive dispatch order, so each input plane is HBM-fetched once/XCD.
__global__ __launch_bounds__(512) void cost_vol_kernel(
    const float* __restrict__ left,
    const float* __restrict__ right,
    float* __restrict__ out)
{
    __shared__ float lds_r[HH][RSTRIDE];   // 40 KB (right blocks only)

    const int bx   = blockIdx.x;           // 0..2047
    const int xcd  = bx & 7;
    const int q    = bx >> 3;               // 0..255
    const int dgrp = q & 7;                 // 0..7
    const int g    = ((q >> 3) << 3) | xcd; // 0..255 = half*128 + b*32 + c
    const int half = g >> 7;
    const int bc   = g & 127;               // b*32 + c
    const int d0   = dgrp * DG;

    const int t  = threadIdx.x;
    const int w0 = (t << 2) & 127;          // column of this thread's float4

    // output group index: b*64 + half*32 + c
    const int ogrp = ((bc >> 5) << 6) | (half << 5) | (bc & 31);
    float* op = out + ((size_t)ogrp * DD + d0) * PLANE + (t << 2);

    if (half == 0) {
        // ---- LEFT: hold the 4 float4s in registers, mask per d, stream out --
        const float* plane = left + (size_t)bc * PLANE + (t << 2);
        const f32x4 l0 = *reinterpret_cast<const f32x4*>(plane);
        const f32x4 l1 = *reinterpret_cast<const f32x4*>(plane + 2048);
        const f32x4 l2 = *reinterpret_cast<const f32x4*>(plane + 4096);
        const f32x4 l3 = *reinterpret_cast<const f32x4*>(plane + 6144);

        #pragma unroll
        for (int dd = 0; dd < DG; ++dd) {
            const int d = d0 + dd;
            const bool m0 = (w0     >= d);
            const bool m1 = (w0 + 1 >= d);
            const bool m2 = (w0 + 2 >= d);
            const bool m3 = (w0 + 3 >= d);
            float* p = op + dd * PLANE;
            f32x4 v;
            v.x = m0 ? l0.x : 0.f; v.y = m1 ? l0.y : 0.f;
            v.z = m2 ? l0.z : 0.f; v.w = m3 ? l0.w : 0.f;
            *reinterpret_cast<f32x4*>(p) = v;
            v.x = m0 ? l1.x : 0.f; v.y = m1 ? l1.y : 0.f;
            v.z = m2 ? l1.z : 0.f; v.w = m3 ? l1.w : 0.f;
            *reinterpret_cast<f32x4*>(p + 2048) = v;
            v.x = m0 ? l2.x : 0.f; v.y = m1 ? l2.y : 0.f;
            v.z = m2 ? l2.z : 0.f; v.w = m3 ? l2.w : 0.f;
            *reinterpret_cast<f32x4*>(p + 4096) = v;
            v.x = m0 ? l3.x : 0.f; v.y = m1 ? l3.y : 0.f;
            v.z = m2 ? l3.z : 0.f; v.w = m3 ? l3.w : 0.f;
            *reinterpret_cast<f32x4*>(p + 6144) = v;
        }
    } else {
        // ---- RIGHT: stage full plane in LDS once, gather for 6 d's ---------
        const float* plane = right + (size_t)bc * PLANE;
        #pragma unroll
        for (int s = 0; s < 4; ++s) {
            const int off = (s << 11) + (t << 2);
            const int h   = off >> 7;
            const int w   = off & 127;
            const f32x4 rv = *reinterpret_cast<const f32x4*>(plane + off);
            lds_r[h][w     +  (w      >> 2)] = rv.x;
            lds_r[h][w + 1 + ((w + 1) >> 2)] = rv.y;
            lds_r[h][w + 2 + ((w + 2) >> 2)] = rv.z;
            lds_r[h][w + 3 + ((w + 3) >> 2)] = rv.w;
        }
        __syncthreads();   // block-uniform branch: safe

        const int hbase = t >> 5;            // 0..15
        #pragma unroll 2
        for (int dd = 0; dd < DG; ++dd) {
            const int d = d0 + dd;
            const int e = w0 - d;
            const int i0 = e,     i1 = e + 1, i2 = e + 2, i3 = e + 3;
            const int x0 = i0 < 0 ? 0 : i0,  x1 = i1 < 0 ? 0 : i1;
            const int x2 = i2 < 0 ? 0 : i2,  x3 = i3 < 0 ? 0 : i3;
            const int s0 = x0 + (x0 >> 2), s1 = x1 + (x1 >> 2);
            const int s2 = x2 + (x2 >> 2), s3 = x3 + (x3 >> 2);
            float* p = op + dd * PLANE;
            #pragma unroll
            for (int s = 0; s < 4; ++s) {
                const int h = (s << 4) + hbase;
                f32x4 v;
                v.x = (i0 >= 0) ? lds_r[h][s0] : 0.f;
                v.y = (i1 >= 0) ? lds_r[h][s1] : 0.f;
                v.z = (i2 >= 0) ? lds_r[h][s2] : 0.f;
                v.w = (i3 >= 0) ? lds_r[h][s3] : 0.f;
                *reinterpret_cast<f32x4*>(p + (s << 11)) = v;
            }
        }
    }
}

extern "C" void kernel_launch(void* const* d_in, const int* in_sizes, int n_in,
                              void* d_out, int out_size, void* d_ws, size_t ws_size,
                              hipStream_t stream) {
    const float* left  = (const float*)d_in[0];
    const float* right = (const float*)d_in[1];
    float* out = (float*)d_out;

    const int grid  = 2 * BB * CC * (DD / DG);   // 2048
    const int block = 512;
    cost_vol_kernel<<<grid, block, 0, stream>>>(left, right, out);
}

// Round 7
// 71.022 us; speedup vs baseline: 1.1113x; 1.1113x over previous
//
#include <hip/hip_runtime.h>

// left/right: [B=4, C=32, H=64, W=128] fp32 ; out: [B, 2C=64, D=48, H, W] fp32
#define BB 4
#define CC 32
#define HH 64
#define WW 128
#define DD 48
#define HT 16                 // h-rows per block
#define RSTRIDE 160           // swizzled LDS row stride

typedef float f32x4 __attribute__((ext_vector_type(4)));

// 1024 blocks x 512 threads (8192 waves = whole chip resident in one shot).
// Block = (half, b, c, hq): ONE output stream per block — left blocks keep
// their float4 in registers (no LDS at all); right blocks stage their 16
// input rows in LDS once (swizzled slot=i+(i>>2): gather stride 5, all 32
// banks) and gather per d. All stores nontemporal (write-once stream, skip
// L2 allocate — the R5-vs-R6 confound suggested NT is worth ~4%).
// Per d: block stores 8 KB contiguous; stream hops 32 KB per d (shown fine
// in R5; R2/R6 proved longer runs don't help).
__global__ __launch_bounds__(512) void cost_vol_kernel(
    const float* __restrict__ left,
    const float* __restrict__ right,
    float* __restrict__ out)
{
    __shared__ float lds_r[HT][RSTRIDE];   // 10 KB, right blocks only

    const int bx   = blockIdx.x;
    const int half = bx & 1;               // alternate halves across XCD rr
    const int idx  = bx >> 1;              // 0..511
    const int hq   = idx & 3;              // H/HT = 4
    const int c    = (idx >> 2) & 31;      // C = 32
    const int b    = idx >> 7;             // B = 4
    const int h0   = hq * HT;

    const int t     = threadIdx.x;
    const int w4    = t & 31;
    const int h_loc = t >> 5;              // 0..15
    const int w0    = w4 << 2;

    const int bc = b * CC + c;

    // out[b][c2][d][h][w], c2 = half*32 + c
    float* op = out +
        ((((size_t)(b * 2 * CC + half * CC + c) * DD) * HH) + h0 + h_loc) * WW + w0;

    if (half == 0) {
        // ---- LEFT: registers only, mask per d, one NT store per iter -------
        const float* lrow = left + ((bc * HH) + h0 + h_loc) * WW;
        const f32x4 lv = *reinterpret_cast<const f32x4*>(lrow + w0);

        #pragma unroll 8
        for (int d = 0; d < DD; ++d) {
            f32x4 v;
            v.x = (w0     >= d) ? lv.x : 0.0f;
            v.y = (w0 + 1 >= d) ? lv.y : 0.0f;
            v.z = (w0 + 2 >= d) ? lv.z : 0.0f;
            v.w = (w0 + 3 >= d) ? lv.w : 0.0f;
            __builtin_nontemporal_store(v, reinterpret_cast<f32x4*>(op));
            op += HH * WW;
        }
    } else {
        // ---- RIGHT: stage 16 rows once, gather per d, one NT store per iter
        {
            const int row = t >> 5;        // 0..15
            const int i0  = (t & 31) << 2;
            const float* rrow = right + ((bc * HH) + h0 + row) * WW;
            const f32x4 rv = *reinterpret_cast<const f32x4*>(rrow + i0);
            lds_r[row][(i0    ) + ((i0    ) >> 2)] = rv.x;
            lds_r[row][(i0 + 1) + ((i0 + 1) >> 2)] = rv.y;
            lds_r[row][(i0 + 2) + ((i0 + 2) >> 2)] = rv.z;
            lds_r[row][(i0 + 3) + ((i0 + 3) >> 2)] = rv.w;
        }
        __syncthreads();                   // block-uniform branch: safe

        const float* rl = lds_r[h_loc];

        #pragma unroll 6
        for (int d = 0; d < DD; ++d) {
            const int e  = w0 - d;
            const int i0 = e,     i1 = e + 1, i2 = e + 2, i3 = e + 3;
            const int x0 = i0 < 0 ? 0 : i0, x1 = i1 < 0 ? 0 : i1;
            const int x2 = i2 < 0 ? 0 : i2, x3 = i3 < 0 ? 0 : i3;
            const float r0 = rl[x0 + (x0 >> 2)];
            const float r1 = rl[x1 + (x1 >> 2)];
            const float r2 = rl[x2 + (x2 >> 2)];
            const float r3 = rl[x3 + (x3 >> 2)];
            f32x4 v;
            v.x = (i0 >= 0) ? r0 : 0.0f;
            v.y = (i1 >= 0) ? r1 : 0.0f;
            v.z = (i2 >= 0) ? r2 : 0.0f;
            v.w = (i3 >= 0) ? r3 : 0.0f;
            __builtin_nontemporal_store(v, reinterpret_cast<f32x4*>(op));
            op += HH * WW;
        }
    }
}

extern "C" void kernel_launch(void* const* d_in, const int* in_sizes, int n_in,
                              void* d_out, int out_size, void* d_ws, size_t ws_size,
                              hipStream_t stream) {
    const float* left  = (const float*)d_in[0];
    const float* right = (const float*)d_in[1];
    float* out = (float*)d_out;

    const int grid  = 2 * BB * CC * (HH / HT);   // 1024
    const int block = 512;
    cost_vol_kernel<<<grid, block, 0, stream>>>(left, right, out);
}